// Round 10
// baseline (167.972 us; speedup 1.0000x reference)
//
#include <hip/hip_runtime.h>
#include <hip/hip_bf16.h>
#include <stdint.h>

// Problem constants (match reference)
#define B_SZ 8
#define T_LEN 1024
#define C_DIM 1024
#define M_ROWS (B_SZ * T_LEN)   // 8192
#define NCH 32
#define CHL (T_LEN / NCH)       // 32

typedef unsigned short ushort_t;
typedef __attribute__((ext_vector_type(8))) short short8;
typedef __attribute__((ext_vector_type(4))) float f32x4;
typedef __attribute__((ext_vector_type(4))) unsigned short us4;

static __device__ __forceinline__ float bf2f(ushort_t u) {
  union { unsigned int i; float f; } x; x.i = ((unsigned int)u) << 16; return x.f;
}
static __device__ __forceinline__ ushort_t f2bf(float f) {
  union { float f; unsigned int i; } x; x.f = f;
  unsigned int r = x.i + 0x7fffu + ((x.i >> 16) & 1u);
  return (ushort_t)(r >> 16);
}

static __device__ __forceinline__ void gload_lds16(const void* g, void* l) {
  __builtin_amdgcn_global_load_lds(
      (const __attribute__((address_space(1))) void*)g,
      (__attribute__((address_space(3))) void*)l, 16, 0, 0);
}

// -------- merged prep: weight f32->bf16 (4 mats) + time-shift mix ----------
__global__ void prep_kernel(const float* __restrict__ wk, const float* __restrict__ wv,
                            const float* __restrict__ wr, const float* __restrict__ wo,
                            ushort_t* __restrict__ wout,
                            const float* __restrict__ x, const float* __restrict__ tm,
                            const float* __restrict__ cm, ushort_t* __restrict__ xmb) {
  if (blockIdx.x < 4096) {
    int gid = blockIdx.x * 256 + threadIdx.x;
    int which = gid >> 18;
    int off = (gid << 2) & ((1 << 20) - 1);
    const float* src = which == 0 ? wk : which == 1 ? wv : which == 2 ? wr : wo;
    float4 v = *(const float4*)(src + off);
    us4 o = {f2bf(v.x), f2bf(v.y), f2bf(v.z), f2bf(v.w)};
    *(us4*)(wout + (size_t)gid * 4) = o;
  } else {
    int gid = (blockIdx.x - 4096) * 256 + threadIdx.x;
    int c4 = (gid & (C_DIM / 4 - 1)) * 4;
    int t = (gid >> 8) & (T_LEN - 1);
    const float4 zero = {0.f, 0.f, 0.f, 0.f};
    float4 xv = *(const float4*)(x + (size_t)gid * 4);
    float4 xp = (t > 0) ? *(const float4*)(x + (size_t)gid * 4 - C_DIM) : zero;
    float4 xn = (t < T_LEN - 1) ? *(const float4*)(x + (size_t)gid * 4 + C_DIM) : zero;
    float4 tmv = *(const float4*)(tm + c4);
    float4 cmv = *(const float4*)(cm + c4);
    float4 xc = (c4 < C_DIM / 2) ? xp : xn;
    us4 o;
    o.x = f2bf(xv.x * tmv.x + xp.x * (1.f - tmv.x) + xc.x * cmv.x);
    o.y = f2bf(xv.y * tmv.y + xp.y * (1.f - tmv.y) + xc.y * cmv.y);
    o.z = f2bf(xv.z * tmv.z + xp.z * (1.f - tmv.z) + xc.z * cmv.z);
    o.w = f2bf(xv.w * tmv.w + xp.w * (1.f - tmv.w) + xc.w * cmv.w);
    *(us4*)(xmb + (size_t)gid * 4) = o;
  }
}

// ======== bf16 NT GEMM, 128x128, BK=64, 2-phase (the measured-best ~690 TF
// structure from gemm_out), templated epilogue. =============================
// FUSED=1: A=xmb, Bw=[Wk|Wv|Wr]; grid 1536; jb 0..23: mode=jb>>3
//          (0:kk bf16 exp-clamp, 1:vv bf16, 2:sr bf16 sigmoid).
// FUSED=0: A=sy, Bw=Wo; grid 512; mode 3 -> f32 d_out.
// Mechanism vs BK=32 variants (R9 post-mortem): 32 MFMA + 16 ds_read per
// vmcnt(0)+barrier drain window -- 2x amortization of the fixed stage/drain/
// barrier cost that dominates the 2-phase critical path (m233). This exact
// structure measured ~690 TF as gemm_out in R5-R9.
// XCD swizzle: xcd=bid&7 owns 8 contiguous bm-panels (2MB A-slice, L2-fit).
// LDS [128][64] rows=128B: G4 XOR swizzle, 16B-chunk = logical^(row&7),
// applied BOTH sides (pre-swizzled global source + swizzled ds_read).
template <int FUSED>
__global__ __launch_bounds__(256, 2) void gemm_bk64(const ushort_t* __restrict__ A,
                                                    const ushort_t* __restrict__ Bw,
                                                    float* __restrict__ outF,
                                                    ushort_t* __restrict__ outK,
                                                    ushort_t* __restrict__ outV,
                                                    ushort_t* __restrict__ outR) {
  constexpr int K = 1024;
  constexpr int NT = K / 64;
  __shared__ ushort_t As[2][128 * 64];
  __shared__ ushort_t Bs[2][128 * 64];

  const int tid = threadIdx.x;
  const int l = tid & 63;
  const int wave = tid >> 6;
  const int fr = l & 15;
  const int kq = l >> 4;

  const int bid = blockIdx.x;
  const int xcd = bid & 7;
  const int idx = bid >> 3;               // fused 0..191 / out 0..63
  const int jb = idx >> 3;                // fused 0..23  / out 0..7
  const int bm = (xcd * 8 + (idx & 7)) * 128;
  const int mode = FUSED ? (jb >> 3) : 3;
  const int bn = FUSED ? (jb & 7) * 128 : jb * 128;
  const ushort_t* Bp = FUSED ? (Bw + ((size_t)(jb >> 3) << 20)) : Bw;

  const int wr = (wave >> 1) * 64;
  const int wc = (wave & 1) * 64;

  f32x4 acc[4][4];
#pragma unroll
  for (int m = 0; m < 4; ++m)
#pragma unroll
    for (int n = 0; n < 4; ++n) acc[m][n] = (f32x4){0.f, 0.f, 0.f, 0.f};

  // staging: per thread 4 A-loads + 4 B-loads (16B each), pre-swizzled source
  int srow[4], scol[4];
#pragma unroll
  for (int j = 0; j < 4; ++j) {
    int row = wave * 32 + j * 8 + (l >> 3);
    srow[j] = row;
    scol[j] = ((l & 7) ^ (row & 7)) * 8;
  }
  const ushort_t* AgB = A + (size_t)bm * K;
  const ushort_t* BgB = Bp + (size_t)bn * K;
  const int dst0 = wave * 2048 + l * 8;

  auto stage = [&](int buf, int k0) {
#pragma unroll
    for (int j = 0; j < 4; ++j)
      gload_lds16(AgB + (size_t)srow[j] * K + scol[j] + k0, &As[buf][dst0 + j * 512]);
#pragma unroll
    for (int j = 0; j < 4; ++j)
      gload_lds16(BgB + (size_t)srow[j] * K + scol[j] + k0, &Bs[buf][dst0 + j * 512]);
  };

  stage(0, 0);
  asm volatile("s_waitcnt vmcnt(0)" ::: "memory");
  __syncthreads();

  const int ps0 = ((0 * 4 + kq) ^ (fr & 7)) * 8;
  const int ps1 = ((1 * 4 + kq) ^ (fr & 7)) * 8;

  int cur = 0;
  for (int t = 0; t < NT; ++t) {
    if (t < NT - 1) stage(cur ^ 1, (t + 1) * 64);
    short8 af[4][2], bfr[4][2];
#pragma unroll
    for (int m = 0; m < 4; ++m) {
      af[m][0] = *(const short8*)&As[cur][(wr + m * 16 + fr) * 64 + ps0];
      af[m][1] = *(const short8*)&As[cur][(wr + m * 16 + fr) * 64 + ps1];
    }
#pragma unroll
    for (int n = 0; n < 4; ++n) {
      bfr[n][0] = *(const short8*)&Bs[cur][(wc + n * 16 + fr) * 64 + ps0];
      bfr[n][1] = *(const short8*)&Bs[cur][(wc + n * 16 + fr) * 64 + ps1];
    }
#pragma unroll
    for (int m = 0; m < 4; ++m)
#pragma unroll
      for (int n = 0; n < 4; ++n)
#pragma unroll
        for (int ks = 0; ks < 2; ++ks)
          acc[m][n] = __builtin_amdgcn_mfma_f32_16x16x32_bf16(af[m][ks], bfr[n][ks], acc[m][n], 0, 0, 0);
    asm volatile("s_waitcnt vmcnt(0)" ::: "memory");
    __syncthreads();
    cur ^= 1;
  }

  // ---- epilogue: C/D layout col=lane&15, row=(lane>>4)*4+j ----
#pragma unroll
  for (int m = 0; m < 4; ++m)
#pragma unroll
    for (int n = 0; n < 4; ++n)
#pragma unroll
      for (int j = 0; j < 4; ++j) {
        float v = acc[m][n][j];
        size_t idx2 = (size_t)(bm + wr + m * 16 + kq * 4 + j) * C_DIM + (bn + wc + n * 16 + fr);
        if (mode == 0) {
          outK[idx2] = f2bf(__expf(fminf(v, 60.f)));
        } else if (mode == 1) {
          outV[idx2] = f2bf(v);
        } else if (mode == 2) {
          outR[idx2] = f2bf(1.f / (1.f + __expf(-v)));
        } else {
          outF[idx2] = v;
        }
      }
}

// ---------------- wkv chunked scan -----------------------------------------
__global__ void wkv_phaseA(const ushort_t* __restrict__ kk, const ushort_t* __restrict__ vv,
                           const float* __restrict__ td,
                           float* __restrict__ sa, float* __restrict__ sb,
                           float* __restrict__ sp) {
  int gid = blockIdx.x * 256 + threadIdx.x;
  int c = gid & (C_DIM - 1);
  int ch = (gid >> 10) & (NCH - 1);
  int b = gid >> 15;
  float w = td[c] * (1.f / T_LEN);
  size_t base = ((size_t)b * T_LEN + ch * CHL) * C_DIM + c;
  float a = 0.f, bb = 0.f, p = -1e38f;
  for (int t = 0; t < CHL; ++t) {
    float kt = bf2f(kk[base + (size_t)t * C_DIM]);
    float vt = bf2f(vv[base + (size_t)t * C_DIM]);
    float no2 = fmaxf(w + p, kt);
    float e1 = __expf(w + p - no2);
    float e2 = __expf(kt - no2);
    a = e1 * a + e2 * vt;
    bb = e1 * bb + e2;
    p = no2;
  }
  sa[gid] = a; sb[gid] = bb; sp[gid] = p;
}

__global__ void wkv_phaseC2(const ushort_t* __restrict__ kk, const ushort_t* __restrict__ vv,
                            const ushort_t* __restrict__ sr, const float* __restrict__ td,
                            const float* __restrict__ tf,
                            const float* __restrict__ sa, const float* __restrict__ sb,
                            const float* __restrict__ sp, ushort_t* __restrict__ sy) {
  int gid = blockIdx.x * 256 + threadIdx.x;
  int c = gid & (C_DIM - 1);
  int ch = (gid >> 10) & (NCH - 1);
  int b = gid >> 15;
  float w = td[c] * (1.f / T_LEN);
  float u = tf[c] * (1.f / T_LEN);
  float wL = w * (float)CHL;

  float a = 0.f, bb = 0.f, p = -1e38f;
  size_t sbase = ((size_t)b * NCH) * C_DIM + c;
  for (int j = 0; j < ch; ++j) {
    float ac = sa[sbase + (size_t)j * C_DIM];
    float bc = sb[sbase + (size_t)j * C_DIM];
    float pc = sp[sbase + (size_t)j * C_DIM];
    float pn = fmaxf(p + wL, pc);
    float e1 = __expf(p + wL - pn);
    float e2 = __expf(pc - pn);
    a = e1 * a + e2 * ac;
    bb = e1 * bb + e2 * bc;
    p = pn;
  }

  size_t base = ((size_t)b * T_LEN + ch * CHL) * C_DIM + c;
  for (int t = 0; t < CHL; ++t) {
    float kt = bf2f(kk[base + (size_t)t * C_DIM]);
    float vt = bf2f(vv[base + (size_t)t * C_DIM]);
    float no = fmaxf(p, u + kt);
    float e1 = __expf(p - no);
    float e2 = __expf(u + kt - no);
    float y = (e1 * a + e2 * vt) / (e1 * bb + e2);
    float srv = bf2f(sr[base + (size_t)t * C_DIM]);
    sy[base + (size_t)t * C_DIM] = f2bf(srv * y);
    float no2 = fmaxf(w + p, kt);
    e1 = __expf(w + p - no2);
    e2 = __expf(kt - no2);
    a = e1 * a + e2 * vt;
    bb = e1 * bb + e2;
    p = no2;
  }
}

// ---------------------------------------------------------------------------
extern "C" void kernel_launch(void* const* d_in, const int* in_sizes, int n_in,
                              void* d_out, int out_size, void* d_ws, size_t ws_size,
                              hipStream_t stream) {
  const float* x  = (const float*)d_in[0];
  const float* td = (const float*)d_in[1];
  const float* tf = (const float*)d_in[2];
  const float* tm = (const float*)d_in[3];
  const float* cm = (const float*)d_in[4];
  const float* Wk = (const float*)d_in[5];
  const float* Wv = (const float*)d_in[6];
  const float* Wr = (const float*)d_in[7];
  const float* Wo = (const float*)d_in[8];

  const size_t MC = (size_t)M_ROWS * C_DIM;
  const size_t CC = (size_t)C_DIM * C_DIM;

  char* ws = (char*)d_ws;
  ushort_t* xmb = (ushort_t*)ws; ws += MC * 2;
  ushort_t* Wb  = (ushort_t*)ws; ws += 4 * CC * 2;
  ushort_t* kk  = (ushort_t*)ws; ws += MC * 2;
  ushort_t* vv  = (ushort_t*)ws; ws += MC * 2;
  ushort_t* sr  = (ushort_t*)ws; ws += MC * 2;
  ushort_t* sy  = (ushort_t*)ws; ws += MC * 2;
  float* sa = (float*)ws; ws += (size_t)B_SZ * NCH * C_DIM * 4;
  float* sb = (float*)ws; ws += (size_t)B_SZ * NCH * C_DIM * 4;
  float* sp = (float*)ws; ws += (size_t)B_SZ * NCH * C_DIM * 4;

  prep_kernel<<<dim3(12288), 256, 0, stream>>>(Wk, Wv, Wr, Wo, Wb, x, tm, cm, xmb);

  // fused k/v/r projections: BK=64 2-phase, 1536 blocks, XCD-swizzled
  gemm_bk64<1><<<dim3(1536), 256, 0, stream>>>(xmb, Wb, nullptr, kk, vv, sr);

  wkv_phaseA<<<(B_SZ * NCH * C_DIM) / 256, 256, 0, stream>>>(kk, vv, td, sa, sb, sp);
  wkv_phaseC2<<<(B_SZ * NCH * C_DIM) / 256, 256, 0, stream>>>(kk, vv, sr, td, tf, sa, sb, sp, sy);

  // output projection: BK=64 2-phase, 512 blocks, XCD-swizzled
  gemm_bk64<0><<<dim3(512), 256, 0, stream>>>(sy, Wb + 3 * CC, (float*)d_out, nullptr, nullptr, nullptr);
}

// Round 11
// 144.589 us; speedup vs baseline: 1.1617x; 1.1617x over previous
//
#include <hip/hip_runtime.h>
#include <hip/hip_bf16.h>
#include <stdint.h>

// Problem constants (match reference)
#define B_SZ 8
#define T_LEN 1024
#define C_DIM 1024
#define M_ROWS (B_SZ * T_LEN)   // 8192
#define NCH 32
#define CHL (T_LEN / NCH)       // 32

typedef unsigned short ushort_t;
typedef __attribute__((ext_vector_type(8))) short short8;
typedef __attribute__((ext_vector_type(4))) float f32x4;
typedef __attribute__((ext_vector_type(4))) unsigned short us4;

static __device__ __forceinline__ float bf2f(ushort_t u) {
  union { unsigned int i; float f; } x; x.i = ((unsigned int)u) << 16; return x.f;
}
static __device__ __forceinline__ ushort_t f2bf(float f) {
  union { float f; unsigned int i; } x; x.f = f;
  unsigned int r = x.i + 0x7fffu + ((x.i >> 16) & 1u);
  return (ushort_t)(r >> 16);
}

static __device__ __forceinline__ void gload_lds16(const void* g, void* l) {
  __builtin_amdgcn_global_load_lds(
      (const __attribute__((address_space(1))) void*)g,
      (__attribute__((address_space(3))) void*)l, 16, 0, 0);
}

// -------- merged prep: weight f32->bf16 (4 mats) + time-shift mix ----------
__global__ void prep_kernel(const float* __restrict__ wk, const float* __restrict__ wv,
                            const float* __restrict__ wr, const float* __restrict__ wo,
                            ushort_t* __restrict__ wout,
                            const float* __restrict__ x, const float* __restrict__ tm,
                            const float* __restrict__ cm, ushort_t* __restrict__ xmb) {
  if (blockIdx.x < 4096) {
    int gid = blockIdx.x * 256 + threadIdx.x;
    int which = gid >> 18;
    int off = (gid << 2) & ((1 << 20) - 1);
    const float* src = which == 0 ? wk : which == 1 ? wv : which == 2 ? wr : wo;
    float4 v = *(const float4*)(src + off);
    us4 o = {f2bf(v.x), f2bf(v.y), f2bf(v.z), f2bf(v.w)};
    *(us4*)(wout + (size_t)gid * 4) = o;
  } else {
    int gid = (blockIdx.x - 4096) * 256 + threadIdx.x;
    int c4 = (gid & (C_DIM / 4 - 1)) * 4;
    int t = (gid >> 8) & (T_LEN - 1);
    const float4 zero = {0.f, 0.f, 0.f, 0.f};
    float4 xv = *(const float4*)(x + (size_t)gid * 4);
    float4 xp = (t > 0) ? *(const float4*)(x + (size_t)gid * 4 - C_DIM) : zero;
    float4 xn = (t < T_LEN - 1) ? *(const float4*)(x + (size_t)gid * 4 + C_DIM) : zero;
    float4 tmv = *(const float4*)(tm + c4);
    float4 cmv = *(const float4*)(cm + c4);
    float4 xc = (c4 < C_DIM / 2) ? xp : xn;
    us4 o;
    o.x = f2bf(xv.x * tmv.x + xp.x * (1.f - tmv.x) + xc.x * cmv.x);
    o.y = f2bf(xv.y * tmv.y + xp.y * (1.f - tmv.y) + xc.y * cmv.y);
    o.z = f2bf(xv.z * tmv.z + xp.z * (1.f - tmv.z) + xc.z * cmv.z);
    o.w = f2bf(xv.w * tmv.w + xp.w * (1.f - tmv.w) + xc.w * cmv.w);
    *(us4*)(xmb + (size_t)gid * 4) = o;
  }
}

// ==== fused k/v/r GEMM: 256x128, BK=32, 8 waves, 3-buf counted vmcnt ========
// Mechanism (R10 ledger): combine the two proven levers — counted-vmcnt 3-buf
// (R4->R6: 105->96) AND 2x MFMA-per-drain amortization (128 MFMA/block-step
// vs 64) at real occupancy (2 blocks/CU, 16 waves/CU; R3/R5/R10 failures all
// had <=1.5 blocks/CU or uneven rounds).
// Geometry: 8 waves as 4M x 2N, wave-tile 64x64 (16 frags, 64 acc VGPR).
// Staging: 3 gload_lds/thread/step (A 2, B 1); LDS 3 x 24KB = 72KB.
// Pipeline: stage(t+2); MFMA(t); vmcnt(3) [stage(t+1) done, stage(t+2) in
// flight]; raw s_barrier.
// XCD swizzle: xcd=bid&7 owns 4 contiguous 256-row bm-panels (2MB, L2-fit).
// LDS slot swizzle (R6-verified): phys 8-elt slot = logical ^ ((row>>1)&3);
// pre-swizzled global source + swizzled ds_read; identity ((row>>1)&3)==
// ((fr>>1)&3) holds (row = 16k + fr).
__global__ __launch_bounds__(512, 4) void gemm_fused(const ushort_t* __restrict__ A,
                                                     const ushort_t* __restrict__ Bw,
                                                     ushort_t* __restrict__ outK,
                                                     ushort_t* __restrict__ outV,
                                                     ushort_t* __restrict__ outR) {
  constexpr int K = 1024;
  __shared__ ushort_t As[3][256 * 32];   // 48 KB
  __shared__ ushort_t Bs[3][128 * 32];   // 24 KB

  const int tid = threadIdx.x;
  const int lane = tid & 63;
  const int wid = tid >> 6;        // 0..7
  const int wm = wid & 3;          // 0..3
  const int wn = wid >> 2;         // 0..1

  const int bid = blockIdx.x;
  const int xcd = bid & 7;
  const int c = bid >> 3;                    // 0..95
  const int bm = (xcd * 4 + (c & 3)) * 256;
  const int jb = c >> 2;                     // 0..23
  const int mode = jb >> 3;                  // 0:k 1:v 2:r
  const int bn = (jb & 7) * 128;
  const ushort_t* Bp = Bw + ((size_t)mode << 20);

  const int wr = wm * 64;
  const int wc = wn * 64;

  f32x4 acc[4][4];
#pragma unroll
  for (int m = 0; m < 4; ++m)
#pragma unroll
    for (int n = 0; n < 4; ++n) acc[m][n] = (f32x4){0.f, 0.f, 0.f, 0.f};

  // staging: A chunks c0=tid, c1=tid+512 (1024 total); B chunk cb=tid (512)
  // chunk -> row = c>>2, pre-swizzled source col = ((c&3)^((c>>3)&3))*8
  const int a0r = tid >> 2, a0c = (((tid & 3) ^ ((tid >> 3) & 3)) * 8);
  const int c1 = tid + 512;
  const int a1r = c1 >> 2, a1c = (((c1 & 3) ^ ((c1 >> 3) & 3)) * 8);
  const ushort_t* Ag0 = A + (size_t)(bm + a0r) * K + a0c;
  const ushort_t* Ag1 = A + (size_t)(bm + a1r) * K + a1c;
  const ushort_t* Bg = Bp + (size_t)(bn + a0r) * K + a0c;   // rows 0..127

  // frag read addressing
  const int fr = lane & 15;
  const int kq = lane >> 4;
  const int ps = (kq ^ ((fr >> 1) & 3)) * 8;

  auto stage = [&](int buf, int kt) {
    const int k0 = kt * 32;
    gload_lds16(Ag0 + k0, &As[buf][tid * 8]);
    gload_lds16(Ag1 + k0, &As[buf][(tid + 512) * 8]);
    gload_lds16(Bg + k0, &Bs[buf][tid * 8]);
  };

#define MFMA_STEP(BUF)                                                        \
  {                                                                           \
    short8 af[4], bfr[4];                                                     \
    _Pragma("unroll") for (int m = 0; m < 4; ++m)                             \
        af[m] = *(const short8*)&As[BUF][(wr + m * 16 + fr) * 32 + ps];       \
    _Pragma("unroll") for (int n = 0; n < 4; ++n)                             \
        bfr[n] = *(const short8*)&Bs[BUF][(wc + n * 16 + fr) * 32 + ps];      \
    _Pragma("unroll") for (int m = 0; m < 4; ++m)                             \
        _Pragma("unroll") for (int n = 0; n < 4; ++n)                         \
            acc[m][n] = __builtin_amdgcn_mfma_f32_16x16x32_bf16(              \
                af[m], bfr[n], acc[m][n], 0, 0, 0);                           \
  }

#define ENDSTEP(N)                                                            \
  asm volatile("s_waitcnt vmcnt(" #N ")" ::: "memory");                       \
  __builtin_amdgcn_s_barrier();                                               \
  __builtin_amdgcn_sched_barrier(0);

#define BODY(ACUR, ASTG, T)                                                   \
  stage(ASTG, (T) + 2);                                                       \
  MFMA_STEP(ACUR);                                                            \
  ENDSTEP(3)

  // prologue: tiles 0,1 in flight (6 loads); vmcnt(3) -> tile0 done
  stage(0, 0);
  stage(1, 1);
  ENDSTEP(3)

#pragma unroll 1
  for (int i = 0; i < 10; ++i) {
    const int t0 = 3 * i;
    BODY(0, 2, t0 + 0)
    BODY(1, 0, t0 + 1)
    BODY(2, 1, t0 + 2)
  }
  // t=30: reads buf0; stage(31) still in flight -> full drain
  MFMA_STEP(0);
  ENDSTEP(0)
  // t=31: reads buf1
  MFMA_STEP(1);

  // ---- epilogue: C/D layout col=lane&15, row=(lane>>4)*4+j ----
#pragma unroll
  for (int m = 0; m < 4; ++m)
#pragma unroll
    for (int n = 0; n < 4; ++n)
#pragma unroll
      for (int j = 0; j < 4; ++j) {
        float v = acc[m][n][j];
        size_t idx = (size_t)(bm + wr + m * 16 + kq * 4 + j) * C_DIM + (bn + wc + n * 16 + fr);
        if (mode == 0) {
          outK[idx] = f2bf(__expf(fminf(v, 60.f)));
        } else if (mode == 1) {
          outV[idx] = f2bf(v);
        } else {
          outR[idx] = f2bf(1.f / (1.f + __expf(-v)));
        }
      }
#undef BODY
#undef ENDSTEP
#undef MFMA_STEP
}

// ============ output GEMM: 128x128 tile, BK=64, 2-phase (R9 form) ==========
__global__ __launch_bounds__(256, 2) void gemm_out(const ushort_t* __restrict__ A,
                                                   const ushort_t* __restrict__ Bw,
                                                   float* __restrict__ outF) {
  constexpr int K = 1024;
  constexpr int NT = K / 64;
  __shared__ ushort_t As[2][128 * 64];
  __shared__ ushort_t Bs[2][128 * 64];

  const int tid = threadIdx.x;
  const int l = tid & 63;
  const int wave = tid >> 6;
  const int fr = l & 15;
  const int kq = l >> 4;

  const int bid = blockIdx.x;
  const int xcd = bid & 7;
  const int idx = bid >> 3;
  const int jb = idx >> 3;
  const int bm = (xcd * 8 + (idx & 7)) * 128;
  const int bn = jb * 128;

  const int wr = (wave >> 1) * 64;
  const int wc = (wave & 1) * 64;

  f32x4 acc[4][4];
#pragma unroll
  for (int m = 0; m < 4; ++m)
#pragma unroll
    for (int n = 0; n < 4; ++n) acc[m][n] = (f32x4){0.f, 0.f, 0.f, 0.f};

  int srow[4], scol[4];
#pragma unroll
  for (int j = 0; j < 4; ++j) {
    int row = wave * 32 + j * 8 + (l >> 3);
    srow[j] = row;
    scol[j] = ((l & 7) ^ (row & 7)) * 8;
  }
  const ushort_t* AgB = A + (size_t)bm * K;
  const ushort_t* BgB = Bw + (size_t)bn * K;
  const int dst0 = wave * 2048 + l * 8;

  auto stage = [&](int buf, int k0) {
#pragma unroll
    for (int j = 0; j < 4; ++j)
      gload_lds16(AgB + (size_t)srow[j] * K + scol[j] + k0, &As[buf][dst0 + j * 512]);
#pragma unroll
    for (int j = 0; j < 4; ++j)
      gload_lds16(BgB + (size_t)srow[j] * K + scol[j] + k0, &Bs[buf][dst0 + j * 512]);
  };

  stage(0, 0);
  asm volatile("s_waitcnt vmcnt(0)" ::: "memory");
  __syncthreads();

  const int ps0 = ((0 * 4 + kq) ^ (fr & 7)) * 8;
  const int ps1 = ((1 * 4 + kq) ^ (fr & 7)) * 8;

  int cur = 0;
  for (int t = 0; t < NT; ++t) {
    if (t < NT - 1) stage(cur ^ 1, (t + 1) * 64);
    short8 af[4][2], bfr[4][2];
#pragma unroll
    for (int m = 0; m < 4; ++m) {
      af[m][0] = *(const short8*)&As[cur][(wr + m * 16 + fr) * 64 + ps0];
      af[m][1] = *(const short8*)&As[cur][(wr + m * 16 + fr) * 64 + ps1];
    }
#pragma unroll
    for (int n = 0; n < 4; ++n) {
      bfr[n][0] = *(const short8*)&Bs[cur][(wc + n * 16 + fr) * 64 + ps0];
      bfr[n][1] = *(const short8*)&Bs[cur][(wc + n * 16 + fr) * 64 + ps1];
    }
#pragma unroll
    for (int m = 0; m < 4; ++m)
#pragma unroll
      for (int n = 0; n < 4; ++n)
#pragma unroll
        for (int ks = 0; ks < 2; ++ks)
          acc[m][n] = __builtin_amdgcn_mfma_f32_16x16x32_bf16(af[m][ks], bfr[n][ks], acc[m][n], 0, 0, 0);
    asm volatile("s_waitcnt vmcnt(0)" ::: "memory");
    __syncthreads();
    cur ^= 1;
  }

#pragma unroll
  for (int m = 0; m < 4; ++m)
#pragma unroll
    for (int n = 0; n < 4; ++n)
#pragma unroll
      for (int j = 0; j < 4; ++j)
        outF[(size_t)(bm + wr + m * 16 + kq * 4 + j) * C_DIM + (bn + wc + n * 16 + fr)] =
            acc[m][n][j];
}

// ---------------- wkv chunked scan -----------------------------------------
__global__ void wkv_phaseA(const ushort_t* __restrict__ kk, const ushort_t* __restrict__ vv,
                           const float* __restrict__ td,
                           float* __restrict__ sa, float* __restrict__ sb,
                           float* __restrict__ sp) {
  int gid = blockIdx.x * 256 + threadIdx.x;
  int c = gid & (C_DIM - 1);
  int ch = (gid >> 10) & (NCH - 1);
  int b = gid >> 15;
  float w = td[c] * (1.f / T_LEN);
  size_t base = ((size_t)b * T_LEN + ch * CHL) * C_DIM + c;
  float a = 0.f, bb = 0.f, p = -1e38f;
  for (int t = 0; t < CHL; ++t) {
    float kt = bf2f(kk[base + (size_t)t * C_DIM]);
    float vt = bf2f(vv[base + (size_t)t * C_DIM]);
    float no2 = fmaxf(w + p, kt);
    float e1 = __expf(w + p - no2);
    float e2 = __expf(kt - no2);
    a = e1 * a + e2 * vt;
    bb = e1 * bb + e2;
    p = no2;
  }
  sa[gid] = a; sb[gid] = bb; sp[gid] = p;
}

__global__ void wkv_phaseC2(const ushort_t* __restrict__ kk, const ushort_t* __restrict__ vv,
                            const ushort_t* __restrict__ sr, const float* __restrict__ td,
                            const float* __restrict__ tf,
                            const float* __restrict__ sa, const float* __restrict__ sb,
                            const float* __restrict__ sp, ushort_t* __restrict__ sy) {
  int gid = blockIdx.x * 256 + threadIdx.x;
  int c = gid & (C_DIM - 1);
  int ch = (gid >> 10) & (NCH - 1);
  int b = gid >> 15;
  float w = td[c] * (1.f / T_LEN);
  float u = tf[c] * (1.f / T_LEN);
  float wL = w * (float)CHL;

  float a = 0.f, bb = 0.f, p = -1e38f;
  size_t sbase = ((size_t)b * NCH) * C_DIM + c;
  for (int j = 0; j < ch; ++j) {
    float ac = sa[sbase + (size_t)j * C_DIM];
    float bc = sb[sbase + (size_t)j * C_DIM];
    float pc = sp[sbase + (size_t)j * C_DIM];
    float pn = fmaxf(p + wL, pc);
    float e1 = __expf(p + wL - pn);
    float e2 = __expf(pc - pn);
    a = e1 * a + e2 * ac;
    bb = e1 * bb + e2 * bc;
    p = pn;
  }

  size_t base = ((size_t)b * T_LEN + ch * CHL) * C_DIM + c;
  for (int t = 0; t < CHL; ++t) {
    float kt = bf2f(kk[base + (size_t)t * C_DIM]);
    float vt = bf2f(vv[base + (size_t)t * C_DIM]);
    float no = fmaxf(p, u + kt);
    float e1 = __expf(p - no);
    float e2 = __expf(u + kt - no);
    float y = (e1 * a + e2 * vt) / (e1 * bb + e2);
    float srv = bf2f(sr[base + (size_t)t * C_DIM]);
    sy[base + (size_t)t * C_DIM] = f2bf(srv * y);
    float no2 = fmaxf(w + p, kt);
    e1 = __expf(w + p - no2);
    e2 = __expf(kt - no2);
    a = e1 * a + e2 * vt;
    bb = e1 * bb + e2;
    p = no2;
  }
}

// ---------------------------------------------------------------------------
extern "C" void kernel_launch(void* const* d_in, const int* in_sizes, int n_in,
                              void* d_out, int out_size, void* d_ws, size_t ws_size,
                              hipStream_t stream) {
  const float* x  = (const float*)d_in[0];
  const float* td = (const float*)d_in[1];
  const float* tf = (const float*)d_in[2];
  const float* tm = (const float*)d_in[3];
  const float* cm = (const float*)d_in[4];
  const float* Wk = (const float*)d_in[5];
  const float* Wv = (const float*)d_in[6];
  const float* Wr = (const float*)d_in[7];
  const float* Wo = (const float*)d_in[8];

  const size_t MC = (size_t)M_ROWS * C_DIM;
  const size_t CC = (size_t)C_DIM * C_DIM;

  char* ws = (char*)d_ws;
  ushort_t* xmb = (ushort_t*)ws; ws += MC * 2;
  ushort_t* Wb  = (ushort_t*)ws; ws += 4 * CC * 2;
  ushort_t* kk  = (ushort_t*)ws; ws += MC * 2;
  ushort_t* vv  = (ushort_t*)ws; ws += MC * 2;
  ushort_t* sr  = (ushort_t*)ws; ws += MC * 2;
  ushort_t* sy  = (ushort_t*)ws; ws += MC * 2;
  float* sa = (float*)ws; ws += (size_t)B_SZ * NCH * C_DIM * 4;
  float* sb = (float*)ws; ws += (size_t)B_SZ * NCH * C_DIM * 4;
  float* sp = (float*)ws; ws += (size_t)B_SZ * NCH * C_DIM * 4;

  prep_kernel<<<dim3(12288), 256, 0, stream>>>(Wk, Wv, Wr, Wo, Wb, x, tm, cm, xmb);

  // fused k/v/r projections: 256x128 tiles, 768 blocks, 3-buf counted vmcnt
  gemm_fused<<<dim3(768), 512, 0, stream>>>(xmb, Wb, kk, vv, sr);

  wkv_phaseA<<<(B_SZ * NCH * C_DIM) / 256, 256, 0, stream>>>(kk, vv, td, sa, sb, sp);
  wkv_phaseC2<<<(B_SZ * NCH * C_DIM) / 256, 256, 0, stream>>>(kk, vv, sr, td, tf, sa, sb, sp, sy);

  // output projection: BK=64 2-phase, 512 blocks, XCD-swizzled
  gemm_out<<<dim3(512), 256, 0, stream>>>(sy, Wb + 3 * CC, (float*)d_out);
}